// Round 2
// baseline (335.622 us; speedup 1.0000x reference)
//
#include <hip/hip_runtime.h>
#include <math.h>

#define NTOT 4608          // N_IN * DIM * DIM
#define NC 16              // n's per chunk
#define NCHUNK (NTOT / NC) // 288

typedef _Float16 f16;
typedef _Float16 f16x8 __attribute__((ext_vector_type(8)));
typedef float f32x4 __attribute__((ext_vector_type(4)));

// ut[b][n][d] (f16) <- x[b][d][n] (f32)
__global__ __launch_bounds__(256) void make_ut(const float* __restrict__ x, f16* __restrict__ ut) {
    const int t = blockIdx.x * 256 + threadIdx.x;       // t = b*4608 + n, < 589824
    const int b = t / NTOT, n = t - b * NTOT;
    f16x8 v;
    #pragma unroll
    for (int d = 0; d < 8; ++d)
        v[d] = (f16)x[((size_t)b * 8 + d) * NTOT + n];
    *reinterpret_cast<f16x8*>(ut + (size_t)t * 8) = v;
}

// wt[n][j][o][d] (f16) <- W[d][o][n][j] (f32)
__global__ __launch_bounds__(256) void make_wt(const float* __restrict__ W, f16* __restrict__ wt) {
    const int t = blockIdx.x * 256 + threadIdx.x;       // t = (n*10 + j)*16 + o, < 737280
    const int n = t / 160;
    const int r = t - n * 160;
    const int j = r >> 4, o = r & 15;
    f16x8 v;
    #pragma unroll
    for (int d = 0; d < 8; ++d)
        v[d] = (f16)W[((size_t)(d * 16 + o) * NTOT + n) * 10 + j];
    *reinterpret_cast<f16x8*>(wt + (size_t)t * 8) = v;
}

// One routing iteration's weighted-sum partials.
// Wave = 16 batch items (N of MFMA), M-tile = j (rows = o), K = d (8 real, padded to 32).
// Lane l: col b = l&15, o-rows = (l>>4)*4 + 0..3.
template<bool FIRST>
__global__ __launch_bounds__(256) void routing_kernel(
    const f16* __restrict__ ut, const f16* __restrict__ wt,
    const float* __restrict__ A, float* __restrict__ partial)
{
    const int lane  = threadIdx.x & 63;
    const int wave  = threadIdx.x >> 6;
    const int chunk = blockIdx.x;
    const int bg    = blockIdx.y * 4 + wave;   // 0..7
    const int b0    = bg * 16;
    const int col   = lane & 15;
    const int og    = lane >> 4;               // o = og*4 + i
    const int b     = b0 + col;
    const bool kact = lane < 16;

    float Areg[10][4];
    if (!FIRST) {
        const float* ap = A + (size_t)b * 160 + og * 4;   // A layout [b][j][o]
        #pragma unroll
        for (int j = 0; j < 10; ++j) {
            f32x4 v = *reinterpret_cast<const f32x4*>(ap + j * 16);
            #pragma unroll
            for (int i = 0; i < 4; ++i) Areg[j][i] = v[i];
        }
    }

    float P[10][4] = {};
    const int n0 = chunk * NC;
    const f16* uptr = ut + ((size_t)(b0 + (lane & 15)) * NTOT + n0) * 8;
    const f32x4 czero = {0.f, 0.f, 0.f, 0.f};

    for (int nl = 0; nl < NC; ++nl) {
        const int n = n0 + nl;
        f16x8 bfrag = {0, 0, 0, 0, 0, 0, 0, 0};
        if (kact) bfrag = *reinterpret_cast<const f16x8*>(uptr + (size_t)nl * 8);

        const f16* wp = wt + (size_t)n * 1280 + (lane & 15) * 8;
        f32x4 C[10];
        #pragma unroll
        for (int j = 0; j < 10; ++j) {
            f16x8 afrag = {0, 0, 0, 0, 0, 0, 0, 0};
            if (kact) afrag = *reinterpret_cast<const f16x8*>(wp + j * 128);
            C[j] = __builtin_amdgcn_mfma_f32_16x16x32_f16(afrag, bfrag, czero, 0, 0, 0);
        }

        if (FIRST) {
            #pragma unroll
            for (int j = 0; j < 10; ++j)
                #pragma unroll
                for (int i = 0; i < 4; ++i) P[j][i] += C[j][i];
        } else {
            float t[10];
            #pragma unroll
            for (int j = 0; j < 10; ++j) {
                float a = Areg[j][0] * C[j][0];
                a = fmaf(Areg[j][1], C[j][1], a);
                a = fmaf(Areg[j][2], C[j][2], a);
                t[j] = fmaf(Areg[j][3], C[j][3], a);
            }
            #pragma unroll
            for (int j = 0; j < 10; ++j) {
                t[j] += __shfl_xor(t[j], 16, 64);
                t[j] += __shfl_xor(t[j], 32, 64);
            }
            float m = t[0];
            #pragma unroll
            for (int j = 1; j < 10; ++j) m = fmaxf(m, t[j]);
            float c[10], s = 0.f;
            #pragma unroll
            for (int j = 0; j < 10; ++j) { c[j] = __expf(t[j] - m); s += c[j]; }
            const float inv = 1.0f / s;
            #pragma unroll
            for (int j = 0; j < 10; ++j) c[j] *= inv;
            #pragma unroll
            for (int j = 0; j < 10; ++j)
                #pragma unroll
                for (int i = 0; i < 4; ++i) P[j][i] = fmaf(c[j], C[j][i], P[j][i]);
        }
    }

    float* pp = partial + ((size_t)chunk * 128 + b) * 160 + og * 4;  // [chunk][b][j][o]
    const float sc = FIRST ? 0.1f : 1.0f;
    #pragma unroll
    for (int j = 0; j < 10; ++j) {
        f32x4 v = {P[j][0] * sc, P[j][1] * sc, P[j][2] * sc, P[j][3] * sc};
        *reinterpret_cast<f32x4*>(pp + j * 16) = v;
    }
}

// Reduce partials over chunks, squash, update A / write out.
// k = j*16 + o. A layout [b][j][o]; out layout [b][o][j].
template<int MODE>   // 0: A = s   1: A += s   2: out = s
__global__ __launch_bounds__(256) void phase2_kernel(
    const float* __restrict__ partial, float* __restrict__ A, float* __restrict__ out)
{
    const int b = blockIdx.x;
    const int k = threadIdx.x;
    __shared__ float sraw[160];
    float acc = 0.f;
    if (k < 160) {
        const float* p = partial + (size_t)b * 160 + k;
        #pragma unroll 8
        for (int c = 0; c < NCHUNK; ++c) acc += p[(size_t)c * 128 * 160];
        sraw[k] = acc;
    }
    __syncthreads();
    if (k < 160) {
        const int j = k >> 4;
        float ssq = 0.f;
        #pragma unroll
        for (int o = 0; o < 16; ++o) { float v = sraw[j * 16 + o]; ssq = fmaf(v, v, ssq); }
        const float scale = ssq / ((1.f + ssq) * sqrtf(ssq));
        const float s = acc * scale;
        if (MODE == 0)      A[(size_t)b * 160 + k] = s;
        else if (MODE == 1) A[(size_t)b * 160 + k] += s;
        else {
            const int o = k & 15;
            out[(size_t)b * 160 + o * 10 + j] = s;
        }
    }
}

extern "C" void kernel_launch(void* const* d_in, const int* in_sizes, int n_in,
                              void* d_out, int out_size, void* d_ws, size_t ws_size,
                              hipStream_t stream) {
    const float* x = (const float*)d_in[0];   // (128, 8, 32, 12, 12)
    const float* W = (const float*)d_in[1];   // (8, 16, 4608, 10)
    float* out = (float*)d_out;               // (128, 16, 10)

    f16* ut = (f16*)d_ws;                                   // 128*4608*8 halves = 9.44 MB
    f16* wt = ut + (size_t)128 * NTOT * 8;                  // 4608*1280 halves  = 11.8 MB
    float* A = (float*)(wt + (size_t)NTOT * 1280);          // 128*160 f32
    float* partial = A + 128 * 160;                         // 288*128*160 f32   = 23.6 MB

    make_ut<<<2304, 256, 0, stream>>>(x, ut);
    make_wt<<<2880, 256, 0, stream>>>(W, wt);

    dim3 g(NCHUNK, 2);
    routing_kernel<true ><<<g, 256, 0, stream>>>(ut, wt, A, partial);
    phase2_kernel<0><<<128, 256, 0, stream>>>(partial, A, out);
    routing_kernel<false><<<g, 256, 0, stream>>>(ut, wt, A, partial);
    phase2_kernel<1><<<128, 256, 0, stream>>>(partial, A, out);
    routing_kernel<false><<<g, 256, 0, stream>>>(ut, wt, A, partial);
    phase2_kernel<2><<<128, 256, 0, stream>>>(partial, A, out);
}

// Round 3
// 187.831 us; speedup vs baseline: 1.7868x; 1.7868x over previous
//
#include <hip/hip_runtime.h>
#include <math.h>

#define NTOT 4608
typedef _Float16 f16;
typedef _Float16 f16x8 __attribute__((ext_vector_type(8)));
typedef float f32x4 __attribute__((ext_vector_type(4)));

// ---- zero the 64KB zero-page (for MFMA K-padding fake loads)
__global__ __launch_bounds__(256) void zero_zp(uint4* zp) {
    zp[blockIdx.x * 256 + threadIdx.x] = make_uint4(0u, 0u, 0u, 0u);
}

// ---- ut[b][n][d] f16 <- x[b][d][n] f32
__global__ __launch_bounds__(256) void make_ut(const float* __restrict__ x, f16* __restrict__ ut) {
    const int t = blockIdx.x * 256 + threadIdx.x;     // b*4608 + n
    const int b = t / NTOT, n = t - b * NTOT;
    f16x8 v;
    #pragma unroll
    for (int d = 0; d < 8; ++d)
        v[d] = (f16)x[((size_t)b * 8 + d) * NTOT + n];
    *reinterpret_cast<f16x8*>(ut + (size_t)t * 8) = v;
}

// ---- wt[n][row][d] f16, row(0..159) = 16*m + 4*q + i; v=4m+i; j=v%10; o=(v/10)*4+q
__global__ __launch_bounds__(256) void make_wt(const float* __restrict__ W, f16* __restrict__ wt) {
    const int t = blockIdx.x * 256 + threadIdx.x;     // n*160 + row
    const int n = t / 160, rr = t - n * 160;
    const int m = rr >> 4, r = rr & 15;
    const int q = r >> 2, i = r & 3;
    const int v = 4 * m + i;
    const int j = v % 10;
    const int o = (v / 10) * 4 + q;
    f16x8 hv;
    #pragma unroll
    for (int d = 0; d < 8; ++d)
        hv[d] = (f16)W[((size_t)(d * 16 + o) * NTOT + n) * 10 + j];
    *reinterpret_cast<f16x8*>(wt + (size_t)t * 8) = hv;
}

// ---- kernel A: u_hat (f16) + iter-0 partial s (c = 0.1 folded later).
// grid (144, 8); block 256 = 4 waves; wave w covers n = chunk*32 + w*8 .. +8, 16 b.
__global__ __launch_bounds__(256) void kernelA(const f16* __restrict__ ut, const f16* __restrict__ wt,
                                               const f16* __restrict__ zp,
                                               f16* __restrict__ uh, float* __restrict__ partial) {
    __shared__ float s0t[4][16][160];
    const int tid = threadIdx.x, w = tid >> 6, lane = tid & 63;
    const int col = lane & 15, qA = lane >> 4;
    const int chunk = blockIdx.x, bg = blockIdx.y, b0 = bg * 16;
    const int nstart = chunk * 32 + w * 8;
    const bool act = lane < 16;

    const f16* ab = act ? (wt + ((size_t)nstart * 160 + col) * 8) : zp;
    const f16* ub = act ? (ut + ((size_t)(b0 + col) * NTOT + nstart) * 8) : zp;
    f16* uhb = uh + ((size_t)(b0 + col) * NTOT + nstart) * 160 + qA * 8;

    const f32x4 cz = {0.f, 0.f, 0.f, 0.f};
    f32x4 s0a[10];
    #pragma unroll
    for (int m = 0; m < 10; ++m) s0a[m] = cz;

    for (int nl = 0; nl < 8; ++nl) {
        f16x8 bf = *reinterpret_cast<const f16x8*>(ub + nl * 8);
        #pragma unroll
        for (int s = 0; s < 5; ++s) {
            f16x8 a0 = *reinterpret_cast<const f16x8*>(ab + ((size_t)nl * 160 + (2 * s) * 16) * 8);
            f16x8 a1 = *reinterpret_cast<const f16x8*>(ab + ((size_t)nl * 160 + (2 * s + 1) * 16) * 8);
            f32x4 C0 = __builtin_amdgcn_mfma_f32_16x16x32_f16(a0, bf, cz, 0, 0, 0);
            f32x4 C1 = __builtin_amdgcn_mfma_f32_16x16x32_f16(a1, bf, cz, 0, 0, 0);
            s0a[2 * s] += C0;
            s0a[2 * s + 1] += C1;
            f16x8 hv;
            hv[0] = (f16)C0[0]; hv[1] = (f16)C0[1]; hv[2] = (f16)C0[2]; hv[3] = (f16)C0[3];
            hv[4] = (f16)C1[0]; hv[5] = (f16)C1[1]; hv[6] = (f16)C1[2]; hv[7] = (f16)C1[3];
            *reinterpret_cast<f16x8*>(uhb + nl * 160 + s * 32) = hv;
        }
    }

    #pragma unroll
    for (int m = 0; m < 10; ++m)
        *reinterpret_cast<f32x4*>(&s0t[w][col][16 * m + 4 * qA]) = s0a[m];
    __syncthreads();
    for (int r = tid; r < 2560; r += 256) {
        const int row = r / 160, slot = r - row * 160;
        float v = s0t[0][row][slot] + s0t[1][row][slot] + s0t[2][row][slot] + s0t[3][row][slot];
        partial[((size_t)chunk * 128 + b0 + row) * 160 + slot] = v;
    }
}

// ---- kernel B: one routing iteration (logits -> softmax -> weighted partial s).
// grid (144, 8); block 256; lane = g*4+q: g = b-local (16), q = oj-quad (4).
__global__ __launch_bounds__(256) void kernelB(const f16* __restrict__ uh, const float* __restrict__ Ar,
                                               float* __restrict__ partial) {
    __shared__ float s1t[4][16][160];
    const int tid = threadIdx.x, w = tid >> 6, lane = tid & 63;
    const int g = lane >> 2, q = lane & 3;
    const int chunk = blockIdx.x, bg = blockIdx.y;
    const int b = bg * 16 + g;
    const int nstart = chunk * 32 + w * 8;

    f32x4 A4[10];
    #pragma unroll
    for (int m = 0; m < 10; ++m)
        A4[m] = *reinterpret_cast<const f32x4*>(Ar + (size_t)b * 160 + 16 * m + 4 * q);

    f32x4 P[10];
    const f32x4 cz = {0.f, 0.f, 0.f, 0.f};
    #pragma unroll
    for (int m = 0; m < 10; ++m) P[m] = cz;

    const f16* uhb = uh + ((size_t)b * NTOT + nstart) * 160 + q * 8;

    for (int nl = 0; nl < 8; ++nl) {
        f16x8 U[5];
        #pragma unroll
        for (int s = 0; s < 5; ++s)
            U[s] = *reinterpret_cast<const f16x8*>(uhb + nl * 160 + s * 32);

        f32x4 uf[10];
        float Lp[10];
        #pragma unroll
        for (int j = 0; j < 10; ++j) Lp[j] = 0.f;
        #pragma unroll
        for (int s = 0; s < 5; ++s) {
            #pragma unroll
            for (int t = 0; t < 8; ++t) {
                const int m = 2 * s + (t >> 2);
                const int i = t & 3;
                const int j = (4 * m + i) % 10;
                const float xv = (float)U[s][t];
                uf[m][i] = xv;
                Lp[j] = fmaf(A4[m][i], xv, Lp[j]);
            }
        }
        #pragma unroll
        for (int j = 0; j < 10; ++j) Lp[j] += __shfl_xor(Lp[j], 1, 64);
        #pragma unroll
        for (int j = 0; j < 10; ++j) Lp[j] += __shfl_xor(Lp[j], 2, 64);

        float mx = Lp[0];
        #pragma unroll
        for (int j = 1; j < 10; ++j) mx = fmaxf(mx, Lp[j]);
        float c[10], sum = 0.f;
        #pragma unroll
        for (int j = 0; j < 10; ++j) { c[j] = __expf(Lp[j] - mx); sum += c[j]; }
        const float inv = 1.0f / sum;
        #pragma unroll
        for (int j = 0; j < 10; ++j) c[j] *= inv;

        #pragma unroll
        for (int m = 0; m < 10; ++m) {
            #pragma unroll
            for (int i = 0; i < 4; ++i)
                P[m][i] = fmaf(c[(4 * m + i) % 10], uf[m][i], P[m][i]);
        }
    }

    #pragma unroll
    for (int m = 0; m < 10; ++m)
        *reinterpret_cast<f32x4*>(&s1t[w][g][16 * m + 4 * q]) = P[m];
    __syncthreads();
    for (int r = tid; r < 2560; r += 256) {
        const int row = r / 160, slot = r - row * 160;
        float v = s1t[0][row][slot] + s1t[1][row][slot] + s1t[2][row][slot] + s1t[3][row][slot];
        partial[((size_t)chunk * 128 + bg * 16 + row) * 160 + slot] = v;
    }
}

// ---- phase2: reduce 144 chunks, squash, update A-state / write output.
// block (160,4); slot k: m=k>>4, r=k&15, q=r>>2, i=r&3, v=4m+i, j=v%10, o=(v/10)*4+q
template<int MODE>   // 0: Ar = s (scale 0.1)   1: Ar += s   2: out = s
__global__ __launch_bounds__(640) void phase2(const float* __restrict__ partial,
                                              float* __restrict__ Ar, float* __restrict__ out,
                                              float scale) {
    const int b = blockIdx.x;
    const int k = threadIdx.x;       // 0..159
    const int y = threadIdx.y;       // 0..3
    __shared__ float sr4[4][160];
    __shared__ float srs[160];
    float a0 = 0.f;
    for (int c = y; c < 144; c += 4)
        a0 += partial[((size_t)c * 128 + b) * 160 + k];
    sr4[y][k] = a0;
    __syncthreads();
    if (y == 0)
        srs[k] = (sr4[0][k] + sr4[1][k] + sr4[2][k] + sr4[3][k]) * scale;
    __syncthreads();
    if (y == 0) {
        const int m = k >> 4, r = k & 15;
        const int q = r >> 2, i = r & 3;
        const int v = 4 * m + i;
        const int j = v % 10;
        const int o = (v / 10) * 4 + q;
        float ssq = 0.f;
        #pragma unroll
        for (int G = 0; G < 4; ++G) {
            const int vv = G * 10 + j;
            const int base = 16 * (vv >> 2) + (vv & 3);
            #pragma unroll
            for (int qq = 0; qq < 4; ++qq) {
                float t = srs[base + 4 * qq];
                ssq = fmaf(t, t, ssq);
            }
        }
        const float s = srs[k] * ssq / ((1.f + ssq) * sqrtf(ssq));
        if (MODE == 0)      Ar[(size_t)b * 160 + k] = s;
        else if (MODE == 1) Ar[(size_t)b * 160 + k] += s;
        else                out[(size_t)b * 160 + o * 10 + j] = s;
    }
}

extern "C" void kernel_launch(void* const* d_in, const int* in_sizes, int n_in,
                              void* d_out, int out_size, void* d_ws, size_t ws_size,
                              hipStream_t stream) {
    const float* x = (const float*)d_in[0];   // (128, 8, 32, 12, 12)
    const float* W = (const float*)d_in[1];   // (8, 16, 4608, 10)
    float* out = (float*)d_out;               // (128, 16, 10)

    f16* zp = (f16*)d_ws;                                    // 64 KB zeros
    f16* ut = zp + 32768;                                    // 128*4608*8      = 9.4 MB
    f16* wt = ut + (size_t)128 * NTOT * 8;                   // 4608*160*8      = 11.8 MB
    f16* uh = wt + (size_t)NTOT * 160 * 8;                   // 128*4608*160    = 188.7 MB
    float* Ar = (float*)(uh + (size_t)128 * NTOT * 160);     // 128*160 f32
    float* partial = Ar + 128 * 160;                         // 144*128*160 f32 = 11.8 MB

    zero_zp<<<16, 256, 0, stream>>>((uint4*)zp);
    make_ut<<<2304, 256, 0, stream>>>(x, ut);
    make_wt<<<2880, 256, 0, stream>>>(W, wt);

    dim3 gA(144, 8), b2(160, 4);
    kernelA<<<gA, 256, 0, stream>>>(ut, wt, zp, uh, partial);
    phase2<0><<<128, b2, 0, stream>>>(partial, Ar, out, 0.1f);
    kernelB<<<gA, 256, 0, stream>>>(uh, Ar, partial);
    phase2<1><<<128, b2, 0, stream>>>(partial, Ar, out, 1.0f);
    kernelB<<<gA, 256, 0, stream>>>(uh, Ar, partial);
    phase2<2><<<128, b2, 0, stream>>>(partial, Ar, out, 1.0f);
}